// Round 1
// baseline (207.260 us; speedup 1.0000x reference)
//
#include <hip/hip_runtime.h>
#include <math.h>

// MRPCEN: multi-rate PCEN.
// x:(B=32,F=128,T=2000) f32; out:(B,4,F,T) f32.
// Strategy: one wave per (b,f) row. The EMA m[k]=(1-s)m[k-1]+s*x[k] is a
// constant-coefficient linear recurrence -> per-lane 32-elem affine compose,
// wave-level Hillis-Steele scan of affines via __shfl_up, replay into LDS,
// then a coalesced epilogue pass computing (x*(eps+M)^-a + d)^r - d^r.

#define NT      4
#define TLEN    2000
#define FDIM    128
#define CHUNK   32
#define LSTRIDE 33        // +1 pad: bank = (lane + j) % 32, 2-way = free
#define ROWPAD  (64 * LSTRIDE)   // 2112 floats per row buffer
#define WAVES_PER_BLOCK 2

__global__ __launch_bounds__(128) void mrpcen_kernel(
    const float* __restrict__ x,
    const float* __restrict__ log_alpha,
    const float* __restrict__ log_delta,
    const float* __restrict__ log_r,
    float* __restrict__ out,
    int rows)
{
    __shared__ float xs[WAVES_PER_BLOCK][ROWPAD];
    __shared__ float Ms[WAVES_PER_BLOCK][ROWPAD];

    const int w    = threadIdx.x >> 6;
    const int lane = threadIdx.x & 63;
    const int row  = blockIdx.x * WAVES_PER_BLOCK + w;   // [0, 4096)
    if (row >= rows) return;
    const int b = row >> 7;       // / FDIM
    const int f = row & (FDIM - 1);

    // ---- load row: coalesced float4 global reads -> swizzled LDS ----
    const float4* xg4 = (const float4*)(x + (size_t)row * TLEN);
    for (int q = lane; q < TLEN / 4; q += 64) {
        float4 v = xg4[q];
        int p0   = q * 4;                               // p0 % 4 == 0, never crosses 32-group
        int bi   = (p0 >> 5) * LSTRIDE + (p0 & 31);
        xs[w][bi + 0] = v.x; xs[w][bi + 1] = v.y;
        xs[w][bi + 2] = v.z; xs[w][bi + 3] = v.w;
    }
    __syncthreads();

    // ---- cache this lane's chunk in registers ----
    float xr[CHUNK];
#pragma unroll
    for (int j = 0; j < CHUNK; ++j)
        xr[j] = xs[w][lane * LSTRIDE + j];              // 2-way bank alias: free

    const float alpha = __expf(log_alpha[f]);
    const float delta = __expf(log_delta[f]);
    const float rr    = __expf(log_r[f]);
    const float dr    = __expf(rr * __logf(delta));     // delta^r
    const float eps   = 1e-5f;

    const float tvals[NT] = {4.f, 16.f, 64.f, 256.f};

#pragma unroll 1
    for (int ti = 0; ti < NT; ++ti) {
        const float t  = tvals[ti];
        const float s  = (sqrtf(1.f + 4.f * t * t) - 1.f) / (2.f * t * t);
        const float cs = 1.f - s;

        // ---- per-lane affine composition over its chunk ----
        // element op: m -> a*m + b, with a=0,b=x[0] at pos 0 (m0 = x[0]),
        // identity past TLEN.
        float A = 1.f, B = 0.f;
#pragma unroll
        for (int j = 0; j < CHUNK; ++j) {
            int pos  = lane * CHUNK + j;
            float a  = (pos < TLEN) ? cs : 1.0f;
            float bb = (pos < TLEN) ? s * xr[j] : 0.0f;
            if (pos == 0) { a = 0.0f; bb = xr[j]; }
            B = fmaf(a, B, bb);
            A = a * A;
        }

        // ---- wave inclusive scan of affines (6 shuffle steps) ----
#pragma unroll
        for (int off = 1; off < 64; off <<= 1) {
            float Ap = __shfl_up(A, off, 64);
            float Bp = __shfl_up(B, off, 64);
            if (lane >= off) {
                B = fmaf(A, Bp, B);
                A = A * Ap;
            }
        }
        // incoming m for this lane's chunk = inclusive B of lane-1
        // (overall A is 0 because element 0 kills the initial value)
        float m = __shfl_up(B, 1, 64);                  // lane 0: unused (a=0 at pos 0)

        // ---- replay chunk, write M into LDS ----
#pragma unroll
        for (int j = 0; j < CHUNK; ++j) {
            int pos  = lane * CHUNK + j;
            float a  = (pos < TLEN) ? cs : 1.0f;
            float bb = (pos < TLEN) ? s * xr[j] : 0.0f;
            if (pos == 0) { a = 0.0f; bb = xr[j]; }
            m = fmaf(a, m, bb);
            if (pos < TLEN) Ms[w][lane * LSTRIDE + j] = m;
        }
        __syncthreads();

        // ---- coalesced epilogue: read x,M from LDS, write out ----
        float* gout = out + ((size_t)(b * NT + ti) * FDIM + f) * TLEN;
        for (int pos = lane; pos < TLEN; pos += 64) {
            int idx      = (pos >> 5) * LSTRIDE + (pos & 31);
            float xv     = xs[w][idx];
            float Mv     = Ms[w][idx];
            // exp(-alpha*(log(eps)+log1p(M/eps))) == (eps+M)^-alpha
            float smooth = __expf(-alpha * __logf(eps + Mv));
            float v      = fmaf(xv, smooth, delta);
            gout[pos]    = __expf(rr * __logf(v)) - dr;
        }
        __syncthreads();
    }
}

extern "C" void kernel_launch(void* const* d_in, const int* in_sizes, int n_in,
                              void* d_out, int out_size, void* d_ws, size_t ws_size,
                              hipStream_t stream) {
    const float* x  = (const float*)d_in[0];
    const float* la = (const float*)d_in[1];
    const float* ld = (const float*)d_in[2];
    const float* lr = (const float*)d_in[3];
    float* out = (float*)d_out;

    const int rows   = in_sizes[0] / TLEN;              // B*F = 4096
    const int blocks = (rows + WAVES_PER_BLOCK - 1) / WAVES_PER_BLOCK;
    hipLaunchKernelGGL(mrpcen_kernel, dim3(blocks), dim3(128), 0, stream,
                       x, la, ld, lr, out, rows);
}

// Round 2
// 177.353 us; speedup vs baseline: 1.1686x; 1.1686x over previous
//
#include <hip/hip_runtime.h>
#include <math.h>

// MRPCEN: multi-rate PCEN. x:(32,128,2000) f32 -> out:(32,4,128,2000) f32.
// One wave per (b,f) row; EMA via affine wave-scan (Hillis-Steele over
// (A,B) pairs); replay fused with pcen epilogue into a single LDS stage
// buffer; coalesced copy-out.
//
// R2 changes vs R1 (occupancy-bound, 16% occ / 43% VALUBusy / 20% HBM):
//  - xs LDS buffer eliminated (x lives in xr[32] registers after load);
//    epilogue fused into replay -> ONE stage buffer, 8448 B/wave.
//  - A-product closed form (cs^32 / cs^16 / 1 / 0) kills one 32-chain.
//  - block=256: 4 waves/block, 33792 B LDS -> 4 blk/CU = 16 waves/CU.

#define NT      4
#define TLEN    2000
#define FDIM    128
#define CHUNK   32
#define LSTRIDE 33               // +1 pad: 2-way bank alias = free
#define ROWPAD  (64 * LSTRIDE)   // 2112 floats
#define WPB     4                // waves per block

__global__ __launch_bounds__(256) void mrpcen_kernel(
    const float* __restrict__ x,
    const float* __restrict__ log_alpha,
    const float* __restrict__ log_delta,
    const float* __restrict__ log_r,
    float* __restrict__ out,
    int rows)
{
    __shared__ float stage[WPB][ROWPAD];

    const int w    = threadIdx.x >> 6;
    const int lane = threadIdx.x & 63;
    const int row  = blockIdx.x * WPB + w;               // [0, 4096)
    const bool live = (row < rows);
    const int b = row >> 7;
    const int f = row & (FDIM - 1);

    // ---- load row coalesced (float4) -> swizzled LDS ----
    if (live) {
        const float4* xg4 = (const float4*)(x + (size_t)row * TLEN);
        for (int q = lane; q < TLEN / 4; q += 64) {
            float4 v = xg4[q];
            int p0 = q * 4;
            int bi = (p0 >> 5) * LSTRIDE + (p0 & 31);
            stage[w][bi + 0] = v.x; stage[w][bi + 1] = v.y;
            stage[w][bi + 2] = v.z; stage[w][bi + 3] = v.w;
        }
    }
    __syncthreads();

    // ---- cache chunk in registers; stage is then dead until replay ----
    float xr[CHUNK];
#pragma unroll
    for (int j = 0; j < CHUNK; ++j)
        xr[j] = stage[w][lane * LSTRIDE + j];

    const int ff = live ? f : 0;
    const float alpha = __expf(log_alpha[ff]);
    const float delta = __expf(log_delta[ff]);
    const float rr    = __expf(log_r[ff]);
    const float dr    = __expf(rr * __logf(delta));      // delta^r
    const float eps   = 1e-5f;

    const float tvals[NT] = {4.f, 16.f, 64.f, 256.f};

#pragma unroll 1
    for (int ti = 0; ti < NT; ++ti) {
        const float t  = tvals[ti];
        const float s  = (sqrtf(1.f + 4.f * t * t) - 1.f) / (2.f * t * t);
        const float cs = 1.f - s;

        // ---- A closed form: prod of a over chunk ----
        // lane 0: pos0 has a=0 -> A=0. lanes 1..61: cs^32.
        // lane 62: 16 live + 16 identity -> cs^16. lane 63: identity -> 1.
        float c2  = cs * cs, c4 = c2 * c2, c8 = c4 * c4;
        float c16 = c8 * c8, c32 = c16 * c16;
        float A = (lane == 0) ? 0.f : (lane < 62) ? c32 : (lane == 62) ? c16 : 1.f;

        // ---- B via single fma chain ----
        float B = 0.f;
#pragma unroll
        for (int j = 0; j < CHUNK; ++j) {
            int pos  = lane * CHUNK + j;
            float a  = (pos < TLEN) ? cs : 1.0f;
            float bb = (pos < TLEN) ? s * xr[j] : 0.0f;
            if (pos == 0) { a = 0.0f; bb = xr[j]; }
            B = fmaf(a, B, bb);
        }

        // ---- wave inclusive scan of affines ----
#pragma unroll
        for (int off = 1; off < 64; off <<= 1) {
            float Ap = __shfl_up(A, off, 64);
            float Bp = __shfl_up(B, off, 64);
            if (lane >= off) {
                B = fmaf(A, Bp, B);
                A = A * Ap;
            }
        }
        float m = __shfl_up(B, 1, 64);                   // incoming state

        // ---- replay fused with pcen epilogue -> stage ----
#pragma unroll
        for (int j = 0; j < CHUNK; ++j) {
            int pos  = lane * CHUNK + j;
            float a  = (pos < TLEN) ? cs : 1.0f;
            float bb = (pos < TLEN) ? s * xr[j] : 0.0f;
            if (pos == 0) { a = 0.0f; bb = xr[j]; }
            m = fmaf(a, m, bb);
            if (pos < TLEN) {
                // exp(-alpha*(log(eps)+log1p(M/eps))) == (eps+M)^-alpha
                float smooth = __expf(-alpha * __logf(eps + m));
                float v      = fmaf(xr[j], smooth, delta);
                stage[w][lane * LSTRIDE + j] = __expf(rr * __logf(v)) - dr;
            }
        }
        __syncthreads();

        // ---- coalesced copy-out ----
        if (live) {
            float* gout = out + ((size_t)(b * NT + ti) * FDIM + f) * TLEN;
            for (int pos = lane; pos < TLEN; pos += 64) {
                int idx = (pos >> 5) * LSTRIDE + (pos & 31);
                gout[pos] = stage[w][idx];
            }
        }
        __syncthreads();   // protect stage from next ti's overwrite
    }
}

extern "C" void kernel_launch(void* const* d_in, const int* in_sizes, int n_in,
                              void* d_out, int out_size, void* d_ws, size_t ws_size,
                              hipStream_t stream) {
    const float* x  = (const float*)d_in[0];
    const float* la = (const float*)d_in[1];
    const float* ld = (const float*)d_in[2];
    const float* lr = (const float*)d_in[3];
    float* out = (float*)d_out;

    const int rows   = in_sizes[0] / TLEN;               // 4096
    const int blocks = (rows + WPB - 1) / WPB;           // 1024
    hipLaunchKernelGGL(mrpcen_kernel, dim3(blocks), dim3(256), 0, stream,
                       x, la, ld, lr, out, rows);
}